// Round 6
// baseline (123.716 us; speedup 1.0000x reference)
//
#include <hip/hip_runtime.h>
#include <stdint.h>

#define BATCH 16
#define CIN   128
#define COUT  128
#define IMG_H 64
#define IMG_W 64
#define HW    4096
#define KTOT  1152          // 9*128
#define XH    66
#define XW    66
#define NCQ   16            // ci groups of 8
#define BM    128
#define BN    64
#define BK    64
#define NSTEPS 18           // 1152/64
#define ASTEP 8192          // A elems per step-tile: 8cq*128co*8e
#define BSTEP 4096          // B elems per step-tile: 8cq*64pix*8e

typedef __attribute__((ext_vector_type(8))) __bf16 bf16x8;
typedef __attribute__((ext_vector_type(4))) float  f32x4;
typedef __attribute__((address_space(1))) const void* gas_p;
typedef __attribute__((address_space(3))) void*       las_p;

static __device__ __forceinline__ unsigned short f2bf(float f) {
  union { float f; uint32_t u; } c; c.f = f;
  uint32_t r = c.u + 0x7fffu + ((c.u >> 16) & 1u);   // RNE
  return (unsigned short)(r >> 16);
}

static __device__ __forceinline__ void gload_lds16(const unsigned short* g, unsigned short* l) {
  __builtin_amdgcn_global_load_lds((gas_p)g, (las_p)l, 16, 0, 0);
}

// ---- fused prep ----
// XCD-pinned decode: bid%16 == b, so bid%8 == b%8 (same XCD as gemm's blocks for b).
// blocks [0, 1024): bid = h*16+b : x fp32 NCHW -> bf16 xpad[b][66][16cq][66][8], zero halo
// blocks [1024, 1312): idx = step*16+b : w fp32 -> wt4[b][step18][cq8][co128][e8]
__global__ void prep_fused(const float* __restrict__ x, const float* __restrict__ w,
                           unsigned short* __restrict__ wt4, unsigned short* __restrict__ xpad) {
  const int t = threadIdx.x;
  if (blockIdx.x < BATCH * IMG_H) {
    // ---------------- prep_x ----------------
    __shared__ uint32_t tile[64 * 68];              // [wcol][ci2], pad 68 words
    const int b = blockIdx.x & 15;
    const int h = blockIdx.x >> 4;
    const float* xb = x + (size_t)b * CIN * HW + h * IMG_W;
    uint4* xp4 = (uint4*)xpad;                      // 16B chunks

    const int lane16 = t & 15;
    const int g      = t >> 4;
#pragma unroll
    for (int it = 0; it < 4; ++it) {
      const int ci = it * 32 + g * 2;
      const float4 va = *(const float4*)(xb + (size_t)ci * HW + lane16 * 4);
      const float4 vb = *(const float4*)(xb + (size_t)(ci + 1) * HW + lane16 * 4);
      const float av[4] = {va.x, va.y, va.z, va.w};
      const float bv[4] = {vb.x, vb.y, vb.z, vb.w};
#pragma unroll
      for (int cc = 0; cc < 4; ++cc)
        tile[(lane16 * 4 + cc) * 68 + it * 16 + g] =
            (uint32_t)f2bf(av[cc]) | ((uint32_t)f2bf(bv[cc]) << 16);
    }
    __syncthreads();

    // interior: chunk o -> cqg = o>>6, wcol = o&63
    const uint32_t rbase = ((uint32_t)b * XH + h + 1) * NCQ;
#pragma unroll
    for (int it = 0; it < 4; ++it) {
      const int o   = it * 256 + t;
      const int cqg = o >> 6;
      const int wc  = o & 63;
      const uint4 v = *(const uint4*)&tile[wc * 68 + cqg * 4];
      xp4[(rbase + cqg) * XW + wc + 1] = v;
    }
    // col halo (w=0, w=65) for this row
    if (t < 32) {
      const int cqg = t & 15;
      const int col = (t >> 4) ? 65 : 0;
      xp4[(rbase + cqg) * XW + col] = make_uint4(0, 0, 0, 0);
    }
    // row halo (rows 0 and 65), done by h==0 blocks
    if (h == 0) {
      const uint32_t r0  = (uint32_t)b * XH * NCQ * XW;
      const uint32_t r65 = ((uint32_t)b * XH + 65) * NCQ * XW;
      for (int i = t; i < NCQ * XW; i += 256) {
        xp4[r0 + i]  = make_uint4(0, 0, 0, 0);
        xp4[r65 + i] = make_uint4(0, 0, 0, 0);
      }
    }
  } else {
    // ---------------- prep_w ----------------
    const int idx  = blockIdx.x - BATCH * IMG_H;    // = step*16 + b
    const int b    = idx & 15;
    const int step = idx >> 4;
    const int khkw = step >> 1;
    const int cib  = (step & 1) << 6;
    const float* wb = w + (size_t)b * COUT * KTOT;
    unsigned short* dst = wt4 + ((size_t)b * NSTEPS + step) * ASTEP;
#pragma unroll
    for (int i = 0; i < 4; ++i) {
      const int c  = i * 256 + t;                 // chunk 0..1023
      const int cq = c >> 7;
      const int co = c & 127;
      const int ci0 = cib + cq * 8;
      const float* src = wb + (size_t)co * KTOT + (size_t)ci0 * 9 + khkw;
      uint32_t p[4];
#pragma unroll
      for (int e = 0; e < 4; ++e)
        p[e] = (uint32_t)f2bf(src[(2 * e) * 9]) | ((uint32_t)f2bf(src[(2 * e + 1) * 9]) << 16);
      *(uint4*)&dst[(size_t)c * 8] = make_uint4(p[0], p[1], p[2], p[3]);
    }
  }
}

// ---- main implicit-GEMM: 128co x 64pix per block, 4 blocks/CU, XCD-pinned ----
__global__ __launch_bounds__(256, 4) void dynconv_gemm(
    const unsigned short* __restrict__ wt4,   // [B][18][8][128][8] bf16
    const unsigned short* __restrict__ xpad,  // [B][66][16][66][8] bf16, halo=0
    float* __restrict__ out) {                // [B][COUT][64][64] fp32
  __shared__ alignas(16) unsigned short As[ASTEP];   // [cq8][co128][8]  16 KB
  __shared__ alignas(16) unsigned short Bs[BSTEP];   // [cq8][pix64][8]   8 KB

  const int t    = threadIdx.x;
  const int b    = blockIdx.x & 15;           // bid%8 == b%8 -> XCD pinning
  const int oh   = blockIdx.x >> 4;           // one output row per block

  const int lane = t & 63;
  const int wave = t >> 6;
  const int wm   = (wave & 1) << 6;           // co offset of wave (0/64)
  const int wn   = (wave >> 1) << 5;          // pixel offset of wave (0/32)
  const int l15  = lane & 15;
  const int quad = lane >> 4;

  // A source: thread's chunk c = i*256 + t at element c*8
  const unsigned short* abase = wt4 + (size_t)b * NSTEPS * ASTEP + (size_t)t * 8;
  // B source: thread-const part ((i*4+wave)*66 + lane)*8 ; step part added below
  const unsigned short* xb = xpad + (size_t)b * XH * NCQ * XW * 8;
  const unsigned short* bbase[2];
#pragma unroll
  for (int i = 0; i < 2; ++i)
    bbase[i] = xb + (size_t)(((i * 4 + wave) * XW) + lane) * 8;

  // LDS staging bases (wave-uniform; HW adds lane*16B)
  unsigned short* alds[4];
  unsigned short* blds[2];
#pragma unroll
  for (int i = 0; i < 4; ++i) alds[i] = &As[(i * 256 + wave * 64) * 8];
#pragma unroll
  for (int i = 0; i < 2; ++i) blds[i] = &Bs[((i * 4 + wave) * 64) * 8];

  f32x4 acc[4][2] = {};

  for (int step = 0; step < NSTEPS; ++step) {
    const int khkw = step >> 1;
    const int kh   = (khkw * 11) >> 5;
    const int kw   = khkw - kh * 3;
    // step part of B address: row = oh+kh, cq-group base = (step&1)*8, col shift kw
    const size_t boff = ((size_t)((oh + kh) * NCQ + ((step & 1) << 3)) * XW + kw) * 8;
    const unsigned short* astep = abase + (size_t)step * ASTEP;

#pragma unroll
    for (int i = 0; i < 4; ++i) gload_lds16(astep + i * 2048, alds[i]);
#pragma unroll
    for (int i = 0; i < 2; ++i) gload_lds16(bbase[i] + boff, blds[i]);
    __syncthreads();

#pragma unroll
    for (int ks = 0; ks < 2; ++ks) {
      const int cq = ks * 4 + quad;
      bf16x8 af[4], bf[2];
#pragma unroll
      for (int i = 0; i < 4; ++i) af[i] = *(const bf16x8*)&As[(cq * 128 + wm + i * 16 + l15) * 8];
#pragma unroll
      for (int j = 0; j < 2; ++j) bf[j] = *(const bf16x8*)&Bs[(cq * 64 + wn + j * 16 + l15) * 8];
#pragma unroll
      for (int i = 0; i < 4; ++i)
#pragma unroll
        for (int j = 0; j < 2; ++j)
          acc[i][j] = __builtin_amdgcn_mfma_f32_16x16x32_bf16(af[i], bf[j], acc[i][j], 0, 0, 0);
    }
    __syncthreads();
  }

  // epilogue: co = wm + i*16 + quad*4 + r; pix = oh*64 + wn + j*16 + l15
  float* obase = out + (size_t)b * COUT * HW + oh * 64;
#pragma unroll
  for (int i = 0; i < 4; ++i) {
#pragma unroll
    for (int r = 0; r < 4; ++r) {
      const int row = wm + i * 16 + quad * 4 + r;
      float* orow = obase + (size_t)row * HW;
#pragma unroll
      for (int j = 0; j < 2; ++j)
        orow[wn + j * 16 + l15] = acc[i][j][r];
    }
  }
}

// ---- safety net: direct fp32 conv ----
__global__ void dynconv_naive(const float* __restrict__ x, const float* __restrict__ w,
                              float* __restrict__ out) {
  const int o   = blockIdx.x * 256 + threadIdx.x;
  const int pix = o & (HW - 1);
  const int co  = (o >> 12) & (COUT - 1);
  const int b   = o >> 19;
  const int oh  = pix >> 6, ow = pix & 63;
  const float* xb = x + (size_t)b * CIN * HW;
  const float* wb = w + ((size_t)b * COUT + co) * CIN * 9;
  float s = 0.f;
  for (int ci = 0; ci < CIN; ++ci) {
    const float* xc = xb + ci * HW;
    const float* wc = wb + ci * 9;
#pragma unroll
    for (int kh = 0; kh < 3; ++kh) {
      const int ih = oh + kh - 1;
      if ((unsigned)ih >= IMG_H) continue;
#pragma unroll
      for (int kw = 0; kw < 3; ++kw) {
        const int iw = ow + kw - 1;
        if ((unsigned)iw >= IMG_W) continue;
        s += xc[ih * IMG_W + iw] * wc[kh * 3 + kw];
      }
    }
  }
  out[o] = s;
}

extern "C" void kernel_launch(void* const* d_in, const int* in_sizes, int n_in,
                              void* d_out, int out_size, void* d_ws, size_t ws_size,
                              hipStream_t stream) {
  const float* x = (const float*)d_in[0];
  const float* w = (const float*)d_in[1];
  float* out = (float*)d_out;

  const size_t wt_bytes = (size_t)BATCH * NSTEPS * ASTEP * sizeof(unsigned short);       //  4.72 MB
  const size_t xp_bytes = (size_t)BATCH * XH * NCQ * XW * 8 * sizeof(unsigned short);    // 17.84 MB

  if (ws_size >= wt_bytes + xp_bytes) {
    unsigned short* wt4  = (unsigned short*)d_ws;
    unsigned short* xpad = (unsigned short*)((char*)d_ws + wt_bytes);
    prep_fused<<<BATCH * IMG_H + BATCH * NSTEPS, 256, 0, stream>>>(x, w, wt4, xpad);
    dynconv_gemm<<<IMG_H * BATCH, 256, 0, stream>>>(wt4, xpad, out);
  } else {
    dynconv_naive<<<(BATCH * COUT * HW) / 256, 256, 0, stream>>>(x, w, out);
  }
}